// Round 18
// baseline (216.172 us; speedup 1.0000x reference)
//
#include <hip/hip_runtime.h>

#define N_NODES 50000
#define N_EDGES 800000

#define SCAN_BLOCKS ((N_NODES + 255) / 256) // 196

static inline size_t alignUp(size_t x, size_t a) { return (x + a - 1) & ~(a - 1); }

// scalar-element ext vector types (R7: HIP vector classes rejected by builtins)
typedef _Float16 h2 __attribute__((ext_vector_type(2)));
typedef _Float16 h4 __attribute__((ext_vector_type(4)));
typedef _Float16 h8 __attribute__((ext_vector_type(8)));
typedef float    fx4 __attribute__((ext_vector_type(4)));

// ---------------- init: zero degree counters + fp16 W^T prep (fused) ----

__global__ void k_init(int* __restrict__ count, const float* __restrict__ W1,
                       const float* __restrict__ W2, const float* __restrict__ W3,
                       _Float16* __restrict__ W1T, _Float16* __restrict__ W2T,
                       _Float16* __restrict__ W3T) {
    int i = blockIdx.x * 256 + threadIdx.x;
    if (i < N_NODES) count[i] = 0;
    if (i < 8192) {            // W1[64][128] -> W1T[128][64]
        int n = i >> 6, k = i & 63;
        W1T[i] = (_Float16)W1[k * 128 + n];
    } else if (i < 24576) {    // W2[128][128] -> W2T[128][128]
        int j = i - 8192; int n = j >> 7, k = j & 127;
        W2T[j] = (_Float16)W2[k * 128 + n];
    } else if (i < 32768) {    // W3[128][64] -> W3T[64][128]
        int j = i - 24576; int n = j >> 7, k = j & 127;
        W3T[j] = (_Float16)W3[k * 64 + n];
    }
}

// ---------------- CSR build (R14 rank-split; R16 4-edge form) ----

__global__ void k_count4(const int* __restrict__ row, int* __restrict__ count,
                         int* __restrict__ rank, int* __restrict__ pad) {
    int i = blockIdx.x * 256 + threadIdx.x;
    if (i < 64) pad[i] = 0;
    if (i < N_EDGES / 4) {
        int4 r = reinterpret_cast<const int4*>(row)[i];
        int k0 = atomicAdd(&count[r.x], 1);
        int k1 = atomicAdd(&count[r.y], 1);
        int k2 = atomicAdd(&count[r.z], 1);
        int k3 = atomicAdd(&count[r.w], 1);
        reinterpret_cast<int4*>(rank)[i] = make_int4(k0, k1, k2, k3);
    }
}

// Fused 3-in-1 scan (R18): each block redundantly computes its prefix base
// over counts[0 .. b*256) (L2-hot, <=50K reads), then scans its own chunk.
// Replaces blocksum + scan_bsum + scan_final (2 fewer launches).
__global__ void k_scan_fused(const int* __restrict__ count, int* __restrict__ offsets,
                             float* __restrict__ dinv) {
    __shared__ int s[256];
    int t = threadIdx.x, b = blockIdx.x;
    // phase 1: base = sum counts[0 .. b*256)
    int partial = 0;
    for (int c = 0; c < b; ++c) partial += count[c * 256 + t];
    s[t] = partial;
    __syncthreads();
    for (int off = 128; off > 0; off >>= 1) {
        if (t < off) s[t] += s[t + off];
        __syncthreads();
    }
    int base = s[0];
    __syncthreads();
    // phase 2: exclusive scan of own chunk
    int i = b * 256 + t;
    int v = (i < N_NODES) ? count[i] : 0;
    s[t] = v;
    __syncthreads();
    for (int off = 1; off < 256; off <<= 1) {
        int add = (t >= off) ? s[t - off] : 0;
        __syncthreads();
        s[t] += add;
        __syncthreads();
    }
    if (i < N_NODES) {
        offsets[i] = base + s[t] - v;
        dinv[i]    = rsqrtf((float)(v + 1)); // +1 self-loop; always > 0
    }
}

// atomic-free scatter + fused fp16 feature prescale
__global__ void k_scatter(const int* __restrict__ row, const int* __restrict__ col,
                          const int* __restrict__ offsets, const int* __restrict__ rank,
                          int* __restrict__ csr_col,
                          const float* __restrict__ feat, const float* __restrict__ dinv,
                          _Float16* __restrict__ featS) {
    int e = blockIdx.x * 256 + threadIdx.x;
    if (e < N_EDGES) {
        int node = e >> 4;
        float d = dinv[node];
        float4 v = reinterpret_cast<const float4*>(feat)[e];
        h4 hv = {(_Float16)(v.x * d), (_Float16)(v.y * d),
                 (_Float16)(v.z * d), (_Float16)(v.w * d)};
        reinterpret_cast<h4*>(featS)[e] = hv;
        int r = row[e];
        csr_col[offsets[r] + rank[e]] = col[e];
    }
}

// ---------------- Fused agg(F=64) + MFMA GEMM1 ----------------
// Block = 1024 thr = 16 waves = 16 nodes (grid 3125: 16*3125 = 50000 exact).
// Per-wave agg identical to R17 k_agg64 (16 lanes x h4, 4 edges/instr,
// 32/batch). Rows staged in LDS (stride 72h: 16B-aligned, bank-rotated),
// then waves 0..7 run GEMM1 col-block w: X1 = fp16(dinv.*relu(A1@W1+b1)).
// No cross-block dep: the GEMM rows ARE the block's aggregated rows.

__global__ __launch_bounds__(1024) void k_agg64_gemm1(const _Float16* __restrict__ hs,
        const _Float16* __restrict__ WT, const float* __restrict__ bias,
        const float* __restrict__ dinv, _Float16* __restrict__ xout,
        const int* __restrict__ csr_col, const int* __restrict__ offsets,
        const int* __restrict__ count) {
    __shared__ _Float16 at[16 * 72];
    int tid = threadIdx.x;
    int wv = tid >> 6;     // 0..15 = node slot
    int lane = tid & 63;
    int node = blockIdx.x * 16 + wv;
    int q = lane >> 4;     // edge sub-slot (0..3)
    int f4 = lane & 15;    // h4 index within 128B row
    const char* base = (const char*)hs;
    uint32_t fo = (uint32_t)f4 << 3;

    int n = __builtin_amdgcn_readfirstlane(count[node]);
    int start = __builtin_amdgcn_readfirstlane(offsets[node]);
    const int* cp = csr_col + start;

    float4 a0 = make_float4(0.f, 0.f, 0.f, 0.f);
    float4 a1 = make_float4(0.f, 0.f, 0.f, 0.f);

    int e = 0;
    for (; e + 32 <= n; e += 32) {
        int c[8];
#pragma unroll
        for (int u = 0; u < 8; u++) c[u] = cp[e + 4 * u + q];
        h4 v[8];
#pragma unroll
        for (int u = 0; u < 8; u++)
            v[u] = *reinterpret_cast<const h4*>(base + (((uint32_t)c[u] << 7) + fo));
#pragma unroll
        for (int u = 0; u < 8; u += 2) {
            a0.x += (float)v[u].x; a0.y += (float)v[u].y;
            a0.z += (float)v[u].z; a0.w += (float)v[u].w;
            a1.x += (float)v[u+1].x; a1.y += (float)v[u+1].y;
            a1.z += (float)v[u+1].z; a1.w += (float)v[u+1].w;
        }
    }
    if (e < n) {
        int c[8];
#pragma unroll
        for (int u = 0; u < 8; u++) c[u] = cp[e + 4 * u + q]; // padded, safe
        h4 v[8];
#pragma unroll
        for (int u = 0; u < 8; u++)
            v[u] = *reinterpret_cast<const h4*>(base + (((uint32_t)c[u] << 7) + fo));
#pragma unroll
        for (int u = 0; u < 8; u++) {
            if (e + 4 * u + q < n) {
                a0.x += (float)v[u].x; a0.y += (float)v[u].y;
                a0.z += (float)v[u].z; a0.w += (float)v[u].w;
            }
        }
    }

    float sx = a0.x + a1.x, sy = a0.y + a1.y, sz = a0.z + a1.z, sw = a0.w + a1.w;
    sx += __shfl_xor(sx, 16); sy += __shfl_xor(sy, 16);
    sz += __shfl_xor(sz, 16); sw += __shfl_xor(sw, 16);
    sx += __shfl_xor(sx, 32); sy += __shfl_xor(sy, 32);
    sz += __shfl_xor(sz, 32); sw += __shfl_xor(sw, 32);
    if (q == 0) {
        h4 self = *reinterpret_cast<const h4*>(base + (((uint32_t)node << 7) + fo));
        float d = dinv[node];
        h4 hv = {(_Float16)((sx + (float)self.x) * d), (_Float16)((sy + (float)self.y) * d),
                 (_Float16)((sz + (float)self.z) * d), (_Float16)((sw + (float)self.w) * d)};
        *reinterpret_cast<h4*>(&at[wv * 72 + f4 * 4]) = hv;
    }
    __syncthreads();

    // GEMM1: waves 0..7, col-block wv (16 cols), K=64 (2 k-steps)
    if (wv < 8) {
        int lm = lane & 15;
        int kb = (lane >> 4) * 8;
        fx4 acc = {0.f, 0.f, 0.f, 0.f};
#pragma unroll
        for (int kk = 0; kk < 2; ++kk) {
            h8 a = *reinterpret_cast<const h8*>(&at[lm * 72 + kk * 32 + kb]);
            h8 b = *reinterpret_cast<const h8*>(WT + (size_t)(wv * 16 + lm) * 64 + kk * 32 + kb);
            acc = __builtin_amdgcn_mfma_f32_16x16x32_f16(a, b, acc, 0, 0, 0);
        }
        int rbase = blockIdx.x * 16 + (lane >> 4) * 4;
        float bv = bias[wv * 16 + lm];
#pragma unroll
        for (int t2 = 0; t2 < 4; ++t2) {
            int gr = rbase + t2; // always < 50000 (3125*16 exact)
            float v = fmaxf(acc[t2] + bv, 0.f) * dinv[gr];
            xout[(size_t)gr * 128 + wv * 16 + lm] = (_Float16)v;
        }
    }
}

// ---------------- Fused agg(F=128) + MFMA GEMM2 ----------------
// Same structure; per-wave agg identical to R17 k_agg128 (64 lanes x h2).
// LDS stride 136h (272B, 16B-aligned). GEMM2: X2 = fp16(relu(A2@W2+b2)).

__global__ __launch_bounds__(1024) void k_agg128_gemm2(const _Float16* __restrict__ hs,
        const _Float16* __restrict__ WT, const float* __restrict__ bias,
        const float* __restrict__ dinv, _Float16* __restrict__ xout,
        const int* __restrict__ csr_col, const int* __restrict__ offsets,
        const int* __restrict__ count) {
    __shared__ _Float16 at[16 * 136];
    int tid = threadIdx.x;
    int wv = tid >> 6;     // 0..15 = node slot
    int lane = tid & 63;
    int node = blockIdx.x * 16 + wv;
    const char* base = (const char*)hs;
    uint32_t lo = (uint32_t)lane << 2; // h2 byte offset within 256B row

    float ax[8], ay[8];
#pragma unroll
    for (int u = 0; u < 8; u++) { ax[u] = 0.f; ay[u] = 0.f; }

    int n = count[node];
    const int* cp = csr_col + offsets[node];

    int e = 0;
    for (; e + 8 <= n; e += 8) {
        int c[8];
#pragma unroll
        for (int u = 0; u < 8; u++) c[u] = cp[e + u];
#pragma unroll
        for (int u = 0; u < 8; u++) {
            h2 v = *reinterpret_cast<const h2*>(base + (((uint32_t)c[u] << 8) + lo));
            ax[u] += (float)v.x; ay[u] += (float)v.y;
        }
    }
    if (e < n) { // one predicated batch covers rem 1..7
        int c[8];
#pragma unroll
        for (int u = 0; u < 8; u++) c[u] = cp[e + u]; // padded, safe
#pragma unroll
        for (int u = 0; u < 8; u++) {
            h2 v = *reinterpret_cast<const h2*>(base + (((uint32_t)c[u] << 8) + lo));
            if (e + u < n) { ax[u] += (float)v.x; ay[u] += (float)v.y; }
        }
    }

    float sx = 0.f, sy = 0.f;
#pragma unroll
    for (int u = 0; u < 8; u++) { sx += ax[u]; sy += ay[u]; }
    h2 self = *reinterpret_cast<const h2*>(base + (((uint32_t)node << 8) + lo));
    float d = dinv[node];
    h2 hv = {(_Float16)((sx + (float)self.x) * d), (_Float16)((sy + (float)self.y) * d)};
    *reinterpret_cast<h2*>(&at[wv * 136 + lane * 2]) = hv;
    __syncthreads();

    // GEMM2: waves 0..7, col-block wv, K=128 (4 k-steps), no scale
    if (wv < 8) {
        int lm = lane & 15;
        int kb = (lane >> 4) * 8;
        fx4 acc = {0.f, 0.f, 0.f, 0.f};
#pragma unroll
        for (int kk = 0; kk < 4; ++kk) {
            h8 a = *reinterpret_cast<const h8*>(&at[lm * 136 + kk * 32 + kb]);
            h8 b = *reinterpret_cast<const h8*>(WT + (size_t)(wv * 16 + lm) * 128 + kk * 32 + kb);
            acc = __builtin_amdgcn_mfma_f32_16x16x32_f16(a, b, acc, 0, 0, 0);
        }
        int rbase = blockIdx.x * 16 + (lane >> 4) * 4;
        float bv = bias[wv * 16 + lm];
#pragma unroll
        for (int t2 = 0; t2 < 4; ++t2) {
            int gr = rbase + t2;
            float v = fmaxf(acc[t2] + bv, 0.f);
            xout[(size_t)gr * 128 + wv * 16 + lm] = (_Float16)v;
        }
    }
}

// ---------------- standalone MFMA GEMM (layer 3) — R17-proven ----------------

template <int K, int NOUT, bool RELU, bool BIAS, bool SCALE>
__global__ __launch_bounds__(256) void k_gemm_mfma(const _Float16* __restrict__ x,
        const _Float16* __restrict__ WT, const float* __restrict__ bias,
        const float* __restrict__ dinv, _Float16* __restrict__ out, int nrows) {
    constexpr int NB = NOUT / 16;
    int l = threadIdx.x & 63;
    int w = threadIdx.x >> 6;
    int lm = l & 15;
    int kb = (l >> 4) * 8;
    int row0 = blockIdx.x * 64 + w * 16;

    int arow = row0 + lm;
    if (arow >= nrows) arow = nrows - 1; // clamp (stores guarded below)

    fx4 acc[NB] = {};

#pragma unroll
    for (int kk = 0; kk < K / 32; ++kk) {
        h8 a = *reinterpret_cast<const h8*>(x + (size_t)arow * K + kk * 32 + kb);
#pragma unroll
        for (int n = 0; n < NB; ++n) {
            h8 b = *reinterpret_cast<const h8*>(WT + (size_t)(n * 16 + lm) * K + kk * 32 + kb);
            acc[n] = __builtin_amdgcn_mfma_f32_16x16x32_f16(a, b, acc[n], 0, 0, 0);
        }
    }

    int rbase = row0 + (l >> 4) * 4;
    float dv[4];
#pragma unroll
    for (int t = 0; t < 4; ++t) {
        int gr = rbase + t;
        dv[t] = SCALE ? dinv[(gr < nrows) ? gr : (nrows - 1)] : 1.f;
    }
#pragma unroll
    for (int n = 0; n < NB; ++n) {
        float bvn = BIAS ? bias[n * 16 + lm] : 0.f;
#pragma unroll
        for (int t = 0; t < 4; ++t) {
            int gr = rbase + t;
            if (gr >= nrows) continue;
            float v = acc[n][t] + bvn;
            if (RELU) v = fmaxf(v, 0.f);
            v *= dv[t];
            out[(size_t)gr * NOUT + n * 16 + lm] = (_Float16)v;
        }
    }
}

// ---------------- final agg(F=64), fp32 out + bias (R17-proven) ----------------

__global__ __launch_bounds__(256) void k_agg64_final(const _Float16* __restrict__ hs,
        float* __restrict__ out, const int* __restrict__ csr_col,
        const int* __restrict__ offsets, const int* __restrict__ count,
        const float* __restrict__ dinv, const float* __restrict__ bias) {
    int lane = threadIdx.x & 63;
    int node = blockIdx.x * 4 + (threadIdx.x >> 6);
    int q = lane >> 4;
    int f4 = lane & 15;
    const char* base = (const char*)hs;
    uint32_t fo = (uint32_t)f4 << 3;

    int n = __builtin_amdgcn_readfirstlane(count[node]);
    int start = __builtin_amdgcn_readfirstlane(offsets[node]);
    const int* cp = csr_col + start;

    float4 a0 = make_float4(0.f, 0.f, 0.f, 0.f);
    float4 a1 = make_float4(0.f, 0.f, 0.f, 0.f);

    int e = 0;
    for (; e + 32 <= n; e += 32) {
        int c[8];
#pragma unroll
        for (int u = 0; u < 8; u++) c[u] = cp[e + 4 * u + q];
        h4 v[8];
#pragma unroll
        for (int u = 0; u < 8; u++)
            v[u] = *reinterpret_cast<const h4*>(base + (((uint32_t)c[u] << 7) + fo));
#pragma unroll
        for (int u = 0; u < 8; u += 2) {
            a0.x += (float)v[u].x; a0.y += (float)v[u].y;
            a0.z += (float)v[u].z; a0.w += (float)v[u].w;
            a1.x += (float)v[u+1].x; a1.y += (float)v[u+1].y;
            a1.z += (float)v[u+1].z; a1.w += (float)v[u+1].w;
        }
    }
    if (e < n) {
        int c[8];
#pragma unroll
        for (int u = 0; u < 8; u++) c[u] = cp[e + 4 * u + q]; // padded, safe
        h4 v[8];
#pragma unroll
        for (int u = 0; u < 8; u++)
            v[u] = *reinterpret_cast<const h4*>(base + (((uint32_t)c[u] << 7) + fo));
#pragma unroll
        for (int u = 0; u < 8; u++) {
            if (e + 4 * u + q < n) {
                a0.x += (float)v[u].x; a0.y += (float)v[u].y;
                a0.z += (float)v[u].z; a0.w += (float)v[u].w;
            }
        }
    }

    float sx = a0.x + a1.x, sy = a0.y + a1.y, sz = a0.z + a1.z, sw = a0.w + a1.w;
    sx += __shfl_xor(sx, 16); sy += __shfl_xor(sy, 16);
    sz += __shfl_xor(sz, 16); sw += __shfl_xor(sw, 16);
    sx += __shfl_xor(sx, 32); sy += __shfl_xor(sy, 32);
    sz += __shfl_xor(sz, 32); sw += __shfl_xor(sw, 32);
    if (q == 0) {
        h4 self = *reinterpret_cast<const h4*>(base + (((uint32_t)node << 7) + fo));
        float d = dinv[node];
        float4 bv = *reinterpret_cast<const float4*>(&bias[f4 * 4]);
        float ox = (sx + (float)self.x) * d + bv.x;
        float oy = (sy + (float)self.y) * d + bv.y;
        float oz = (sz + (float)self.z) * d + bv.z;
        float ow = (sw + (float)self.w) * d + bv.w;
        *reinterpret_cast<float4*>((char*)out + ((uint32_t)node << 8) + (fo << 1)) =
            make_float4(ox, oy, oz, ow);
    }
}

// ---------------- launch ----------------

extern "C" void kernel_launch(void* const* d_in, const int* in_sizes, int n_in,
                              void* d_out, int out_size, void* d_ws, size_t ws_size,
                              hipStream_t stream) {
    const float* feat = (const float*)d_in[0]; // [N, 64]
    const float* W1 = (const float*)d_in[1];   // [64, 128]
    const float* b1 = (const float*)d_in[2];
    const float* W2 = (const float*)d_in[3];   // [128, 128]
    const float* b2 = (const float*)d_in[4];
    const float* W3 = (const float*)d_in[5];   // [128, 64]
    const float* b3 = (const float*)d_in[6];
    const int* ei = (const int*)d_in[7];       // [2, E]
    const int* row = ei;
    const int* col = ei + N_EDGES;
    float* out = (float*)d_out;

    // workspace bump allocator (256B aligned)
    char* ws = (char*)d_ws;
    size_t off = 0;
    auto alloc = [&](size_t bytes) {
        void* p = ws + off;
        off = alignUp(off + bytes, 256);
        return p;
    };
    constexpr size_t SLOT = (size_t)N_NODES * 128 * 2; // 12.8 MB fp16 slot
    _Float16* S1 = (_Float16*)alloc(SLOT); // featS -> X2
    _Float16* S2 = (_Float16*)alloc(SLOT); // X1 -> H3
    float* dinv    = (float*)alloc((size_t)N_NODES * 4);
    int*   count   = (int*)alloc((size_t)N_NODES * 4);
    int*   offsets = (int*)alloc((size_t)N_NODES * 4);
    int*   rank    = (int*)alloc((size_t)N_EDGES * 4);
    int*   csr_col = (int*)alloc((size_t)(N_EDGES + 64) * 4); // +64 pad
    _Float16* W1T  = (_Float16*)alloc(128 * 64 * 2);
    _Float16* W2T  = (_Float16*)alloc(128 * 128 * 2);
    _Float16* W3T  = (_Float16*)alloc(64 * 128 * 2);

    _Float16* featS = S1; // dead after layer-1 agg phase
    _Float16* X1h = S2;
    _Float16* X2h = S1;   // overwrites featS (dead)
    _Float16* H3h = S2;   // overwrites X1 (dead)

    const int eb = (N_EDGES + 255) / 256;       // 3125
    const int cb4 = (N_EDGES / 4 + 255) / 256;  // 782
    const int fb = (N_NODES + 15) / 16;         // 3125 (fused agg+gemm blocks)

    // 1. init: zero counters + W^T fp16 prep
    k_init<<<SCAN_BLOCKS, 256, 0, stream>>>(count, W1, W2, W3, W1T, W2T, W3T);
    // 2. degree count + per-edge rank (atomic returns)
    k_count4<<<cb4, 256, 0, stream>>>(row, count, rank, csr_col + N_EDGES);
    // 3. fused exclusive scan + dinv
    k_scan_fused<<<SCAN_BLOCKS, 256, 0, stream>>>(count, offsets, dinv);
    // 4. atomic-free scatter + fp16 feature prescale
    k_scatter<<<eb, 256, 0, stream>>>(row, col, offsets, rank, csr_col, feat, dinv, featS);
    // 5. layer 1: agg(F=64) + GEMM1 fused -> X1 (fp16)
    k_agg64_gemm1<<<fb, 1024, 0, stream>>>(featS, W1T, b1, dinv, X1h, csr_col, offsets, count);
    // 6. layer 2: agg(F=128) + GEMM2 fused -> X2 (fp16)
    k_agg128_gemm2<<<fb, 1024, 0, stream>>>(X1h, W2T, b2, dinv, X2h, csr_col, offsets, count);
    // 7. layer 3 GEMM: H3 = fp16(dinv .* (X2@W3))
    k_gemm_mfma<128, 64, false, false, true><<<(N_NODES + 63) / 64, 256, 0, stream>>>(
        X2h, W3T, nullptr, dinv, H3h, N_NODES);
    // 8. final agg(F=64) + b3 -> out (fp32)
    k_agg64_final<<<N_NODES / 4, 256, 0, stream>>>(H3h, out, csr_col, offsets, count, dinv, b3);
}